// Round 1
// baseline (762.683 us; speedup 1.0000x reference)
//
#include <hip/hip_runtime.h>
#include <math.h>

#define B_ 4
#define S_ 2
#define P_ 17
#define H_ 128
#define W_ 128
#define TAG_ 1
#define M_ 8
#define K_ 10
#define HW_ (H_*W_)
#define PHW_ (P_*HW_)
#define CH_ ((1+TAG_)*P_)      // 34 channels in preds
#define E_INV_F 0.36787944117144233f
#define SF_ 3.0f
#define INV2SIG 12.5f          // 1/(2*0.2^2)
#define MAXDIST 256.0f         // H+W

__global__ void k_init(float* out) { out[0] = 0.0f; }

// ---------------- det_loss: mean over B,S,P,H,W of wgt*bce ----------------
__global__ __launch_bounds__(256) void k_det(const float* __restrict__ preds,
                                             const float* __restrict__ gmask,
                                             const float* __restrict__ gh,
                                             float* __restrict__ out) {
    const int N = B_*S_*P_*HW_;
    float acc = 0.0f;
    for (int i = blockIdx.x*256 + threadIdx.x; i < N; i += gridDim.x*256) {
        int hw = i & (HW_-1);
        int t1 = i >> 14;            // / HW_
        int p  = t1 % P_;
        int t2 = t1 / P_;
        int s  = t2 % S_;
        int b  = t2 / S_;
        float hm = preds[((b*S_+s)*CH_ + p)*HW_ + hw];
        // numerically-stable sigmoid (matches jax.nn.sigmoid)
        float prob;
        if (hm >= 0.0f) { prob = 1.0f/(1.0f + expf(-hm)); }
        else            { float e = expf(hm); prob = e/(1.0f + e); }
        float msk = gmask[b*HW_ + hw];
        float ghv = gh[(b*P_ + p)*HW_ + hw];
        float x = prob * msk;
        float t   = (ghv > E_INV_F) ? 1.0f : 0.0f;
        float wgt = 10.0f*t + ((ghv < E_INV_F) ? 0.5f : 0.0f);
        float lx  = fmaxf(logf(x),        -100.0f);
        float l1x = fmaxf(logf(1.0f - x), -100.0f);
        float bce = -(t*lx + (1.0f - t)*l1x);
        acc += wgt * bce;
    }
    // wave + block reduce
    #pragma unroll
    for (int off = 32; off > 0; off >>= 1) acc += __shfl_down(acc, off);
    __shared__ float sred[4];
    int wave = threadIdx.x >> 6, lane = threadIdx.x & 63;
    if (lane == 0) sred[wave] = acc;
    __syncthreads();
    if (threadIdx.x == 0) {
        float sum = sred[0] + sred[1] + sred[2] + sred[3];
        atomicAdd(out, sum * (1.0f/(float)N));
    }
}

// ---------------- push/pull tag loss: one block per (b,s) ----------------
__global__ __launch_bounds__(256) void k_tag(const float* __restrict__ preds,
                                             const int* __restrict__ kp,
                                             float* __restrict__ out) {
    int bs = blockIdx.x; int s = bs % S_; int b = bs / S_;
    __shared__ float g[M_*P_];
    __shared__ float vis[M_*P_];
    __shared__ float mean_tag[M_];
    __shared__ float validm[M_];
    __shared__ float pull_pp[M_];
    int tid = threadIdx.x;
    const float* tagbase = preds + ((size_t)(b*S_+s)*CH_ + P_)*HW_;
    if (tid < M_*P_) {
        int m = tid / P_; int p = tid % P_;
        int off = ((b*M_ + m)*P_ + p)*2;
        int idx = kp[off];
        int v   = kp[off+1];
        g[tid]   = tagbase[idx];
        vis[tid] = (v > 0) ? 1.0f : 0.0f;
    }
    __syncthreads();
    if (tid < M_) {
        float cnt = 0.0f, sum = 0.0f;
        for (int p = 0; p < P_; p++) { cnt += vis[tid*P_+p]; sum += g[tid*P_+p]*vis[tid*P_+p]; }
        float safe = fmaxf(cnt, 1.0f);
        float mt = sum / safe;
        mean_tag[tid] = mt;
        validm[tid] = (cnt > 0.0f) ? 1.0f : 0.0f;
        float pp = 0.0f;
        for (int p = 0; p < P_; p++) { float d = g[tid*P_+p] - mt; pp += d*d*vis[tid*P_+p]; }
        pull_pp[tid] = pp / (safe * (float)TAG_);
    }
    __syncthreads();
    if (tid == 0) {
        float num = 0.0f;
        for (int m = 0; m < M_; m++) num += validm[m];
        float pull = 0.0f;
        for (int m = 0; m < M_; m++) pull += pull_pp[m]*validm[m];
        pull = pull / (num + 1e-6f);
        float pmsum = 0.0f;
        for (int i = 0; i < M_; i++)
            for (int j = 0; j < M_; j++) {
                float d = mean_tag[i] - mean_tag[j]; d = d*d;
                pmsum += expf(-d)*validm[i]*validm[j];
            }
        float push = (pmsum - num) / ((num - 1.0f)*num + 1e-6f) * 0.5f;
        atomicAdd(out, (push + pull) * (1.0f/(float)(B_*S_)));
    }
}

// ---------------- top-K + person_id: one block per (b,s) ----------------
__global__ __launch_bounds__(256) void k_topk(const float* __restrict__ preds,
                                              const float* __restrict__ gsk,
                                              float* __restrict__ ws_tv,
                                              int* __restrict__ ws_pid) {
    int bs = blockIdx.x; int s = bs % S_; int b = bs / S_;
    const float* hmbase  = preds + (size_t)(b*S_+s)*CH_*HW_;
    const float* tagbase = hmbase + (size_t)P_*HW_;
    int tid = threadIdx.x;
    // local top-10 (sigmoid is monotone -> order by raw hm)
    float v[K_]; int id[K_];
    #pragma unroll
    for (int j = 0; j < K_; j++) { v[j] = -INFINITY; id[j] = 0x7fffffff; }
    for (int i = tid; i < PHW_; i += 256) {
        float x = hmbase[i];
        if (x > v[K_-1]) {
            int j = K_-1;
            while (j > 0 && v[j-1] < x) { v[j] = v[j-1]; id[j] = id[j-1]; j--; }
            v[j] = x; id[j] = i;
        }
    }
    __shared__ float sv[256*K_];
    __shared__ int   si[256*K_];
    __shared__ float rv[256];
    __shared__ int   rp[256];
    __shared__ int   s_top[K_];
    #pragma unroll
    for (int j = 0; j < K_; j++) { sv[tid*K_+j] = v[j]; si[tid*K_+j] = id[j]; }
    __syncthreads();
    for (int r = 0; r < K_; r++) {
        // local argmax over my 10 LDS entries (tie -> smaller original index)
        float bv = sv[tid*K_]; int bp = tid*K_;
        for (int j = 1; j < K_; j++) {
            int p = tid*K_ + j; float x = sv[p];
            if (x > bv || (x == bv && si[p] < si[bp])) { bv = x; bp = p; }
        }
        rv[tid] = bv; rp[tid] = bp;
        __syncthreads();
        for (int st = 128; st > 0; st >>= 1) {
            if (tid < st) {
                float ov = rv[tid+st]; int op = rp[tid+st];
                if (ov > rv[tid] || (ov == rv[tid] && si[op] < si[rp[tid]])) { rv[tid] = ov; rp[tid] = op; }
            }
            __syncthreads();
        }
        if (tid == 0) { int p = rp[0]; s_top[r] = si[p]; sv[p] = -INFINITY; }
        __syncthreads();
    }
    if (tid < K_) {
        int topi = s_top[tid];
        int part = topi / HW_;
        int rem  = topi & (HW_-1);
        int xi   = rem >> 7;       // / W_
        int yi   = rem & (W_-1);
        float tv = tagbase[topi];
        // argmin over M of dist
        float best = INFINITY; int pid = 0;
        for (int m = 0; m < M_; m++) {
            const float* sk = gsk + ((size_t)(b*M_ + m)*P_ + part)*3;
            float sk1 = sk[1], sk2 = sk[2];
            float vp = (sk2 == 1.0f) ? MAXDIST : 0.0f;
            float d0 = vp + sk1 - (float)xi;
            float d1 = vp + sk2 - (float)yi;
            float dist = sqrtf(d0*d0 + d1*d1 + 1e-12f);
            if (dist < best) { best = dist; pid = m; }
        }
        int o = bs*K_ + tid;
        ws_tv[o]  = tv;
        ws_pid[o] = pid;
    }
}

// ---------------- skel loss: one block per (b,s,p); K online-softmaxes ----------------
__global__ __launch_bounds__(256) void k_skel(const float* __restrict__ preds,
                                              const float* __restrict__ gsk,
                                              const float* __restrict__ ws_tv,
                                              const int* __restrict__ ws_pid,
                                              float* __restrict__ out) {
    int bid = blockIdx.x;                 // over B*S*P
    int p  = bid % P_;
    int bs = bid / P_;
    int s  = bs % S_;
    int b  = bs / S_;
    const float* hmp = preds + ((size_t)(b*S_+s)*CH_ + p)*HW_;
    const float* tgp = preds + ((size_t)(b*S_+s)*CH_ + P_ + p)*HW_;
    float tv[K_];
    #pragma unroll
    for (int k = 0; k < K_; k++) tv[k] = ws_tv[bs*K_ + k];
    float m[K_], l[K_], sx[K_], sy[K_];
    #pragma unroll
    for (int k = 0; k < K_; k++) { m[k] = -INFINITY; l[k] = 0.0f; sx[k] = 0.0f; sy[k] = 0.0f; }
    int tid = threadIdx.x;
    for (int pix = tid; pix < HW_; pix += 256) {
        float hm = hmp[pix];
        float tg = tgp[pix];
        float a = SF_*hm;
        float h = (float)(pix >> 7);      // row index
        float w = (float)(pix & (W_-1));  // col index
        #pragma unroll
        for (int k = 0; k < K_; k++) {
            float d = tg - tv[k];
            float logit = a - d*d*INV2SIG;
            if (logit > m[k]) {
                float sc = __expf(m[k] - logit);
                l[k]  = l[k]*sc + 1.0f;
                sx[k] = sx[k]*sc + h;
                sy[k] = sy[k]*sc + w;
                m[k]  = logit;
            } else {
                float e = __expf(logit - m[k]);
                l[k] += e; sx[k] += e*h; sy[k] += e*w;
            }
        }
    }
    // wave reduce (every lane processed 64 pixels -> all m finite)
    #pragma unroll
    for (int k = 0; k < K_; k++) {
        for (int off = 32; off > 0; off >>= 1) {
            float m2  = __shfl_down(m[k],  off);
            float l2  = __shfl_down(l[k],  off);
            float sx2 = __shfl_down(sx[k], off);
            float sy2 = __shfl_down(sy[k], off);
            float nm = fmaxf(m[k], m2);
            float e1 = __expf(m[k] - nm), e2 = __expf(m2 - nm);
            l[k]  = l[k]*e1  + l2*e2;
            sx[k] = sx[k]*e1 + sx2*e2;
            sy[k] = sy[k]*e1 + sy2*e2;
            m[k] = nm;
        }
    }
    __shared__ float red[4][K_][4];
    int wave = tid >> 6, lane = tid & 63;
    if (lane == 0) {
        for (int k = 0; k < K_; k++) {
            red[wave][k][0] = m[k]; red[wave][k][1] = l[k];
            red[wave][k][2] = sx[k]; red[wave][k][3] = sy[k];
        }
    }
    __syncthreads();
    if (tid < K_) {
        int k = tid;
        float M0 = red[0][k][0], L = red[0][k][1], SX = red[0][k][2], SY = red[0][k][3];
        for (int w2 = 1; w2 < 4; w2++) {
            float m2 = red[w2][k][0], l2 = red[w2][k][1], sx2 = red[w2][k][2], sy2 = red[w2][k][3];
            float nm = fmaxf(M0, m2);
            float e1 = __expf(M0 - nm), e2 = __expf(m2 - nm);
            L = L*e1 + l2*e2; SX = SX*e1 + sx2*e2; SY = SY*e1 + sy2*e2; M0 = nm;
        }
        float px = SX / L, py = SY / L;
        int pid = ws_pid[bs*K_ + k];
        const float* g = gsk + ((size_t)(b*M_ + pid)*P_ + p)*3;
        float d0 = g[0] - px, d1 = g[1] - py;
        float gate = (g[2] > 0.0f) ? 1.0f : 0.0f;
        float err = sqrtf(d0*d0 + d1*d1 + 1e-12f) * gate;
        float hub = (err < 0.1f) ? err*err : 0.1f*(err - 0.05f);
        atomicAdd(out, hub * (10.0f/(float)(B_*S_*K_*P_)));
    }
}

extern "C" void kernel_launch(void* const* d_in, const int* in_sizes, int n_in,
                              void* d_out, int out_size, void* d_ws, size_t ws_size,
                              hipStream_t stream) {
    (void)in_sizes; (void)n_in; (void)out_size; (void)ws_size;
    const float* preds = (const float*)d_in[0];
    const float* gmask = (const float*)d_in[1];
    const float* gh    = (const float*)d_in[2];
    const float* gsk   = (const float*)d_in[3];
    const int*   gkp   = (const int*)d_in[4];
    float* out = (float*)d_out;
    float* ws_tv = (float*)d_ws;
    int*   ws_pid = (int*)((char*)d_ws + (size_t)B_*S_*K_*sizeof(float));

    hipLaunchKernelGGL(k_init, dim3(1), dim3(1), 0, stream, out);
    hipLaunchKernelGGL(k_det,  dim3(2176), dim3(256), 0, stream, preds, gmask, gh, out);
    hipLaunchKernelGGL(k_tag,  dim3(B_*S_), dim3(256), 0, stream, preds, gkp, out);
    hipLaunchKernelGGL(k_topk, dim3(B_*S_), dim3(256), 0, stream, preds, gsk, ws_tv, ws_pid);
    hipLaunchKernelGGL(k_skel, dim3(B_*S_*P_), dim3(256), 0, stream, preds, gsk, ws_tv, ws_pid, out);
}

// Round 2
// 162.505 us; speedup vs baseline: 4.6933x; 4.6933x over previous
//
#include <hip/hip_runtime.h>
#include <math.h>

#define B_ 4
#define S_ 2
#define P_ 17
#define H_ 128
#define W_ 128
#define M_ 8
#define K_ 10
#define HW_ (H_*W_)
#define PHW_ (P_*HW_)
#define CH_ 34                 // (1+TAG)*P channels in preds
#define G_ 34                  // chunks per (b,s) for top-k phase 1
#define C_ (PHW_/G_)           // 8192 elements per chunk
#define E_INV_F 0.36787944117144233f
#define LOG2E 1.4426950408889634f
#define SF_ 3.0f
#define INV2SIG 12.5f          // 1/(2*0.2^2)
#define MAXDIST 256.0f         // H+W

// ---- packed sort key: monotone float map (hi) | ~index (lo) ----
// larger key == larger value, ties -> smaller index (matches jax top_k)
__device__ __forceinline__ unsigned long long pack_key(float f, unsigned int i) {
    unsigned int u = __float_as_uint(f);
    u = (u & 0x80000000u) ? ~u : (u | 0x80000000u);
    return ((unsigned long long)u << 32) | (unsigned int)(~i);
}

// branch-free insert into sorted-descending a[0..9]; caller guarantees key > a[9]
__device__ __forceinline__ void insert10(unsigned long long* a, unsigned long long key) {
    #pragma unroll
    for (int j = 9; j >= 1; --j) {
        unsigned long long am1 = a[j-1];
        a[j] = (key > am1) ? am1 : ((key > a[j]) ? key : a[j]);
    }
    a[0] = (key > a[0]) ? key : a[0];
}

// merge sorted list b into sorted list a (both desc, 10 entries)
__device__ __forceinline__ void merge10(unsigned long long* a, const unsigned long long* b) {
    #pragma unroll
    for (int t = 0; t < 10; ++t) {
        unsigned long long key = b[t];
        if (key > a[9]) insert10(a, key);
    }
}

// ---------------- top-k phase 1: per-chunk top-10 ----------------
// grid = B*S*G_, block 256. Also zero-inits out[0] (block 0).
__global__ __launch_bounds__(256) void k_top1(const float* __restrict__ preds,
                                              unsigned long long* __restrict__ cand,
                                              float* __restrict__ out) {
    if (blockIdx.x == 0 && threadIdx.x == 0) out[0] = 0.0f;
    int bs = blockIdx.x / G_;
    int c  = blockIdx.x % G_;
    const float4* base = (const float4*)(preds + (size_t)bs*CH_*HW_ + (size_t)c*C_);
    int tid = threadIdx.x;
    unsigned long long a[10];
    #pragma unroll
    for (int j = 0; j < 10; ++j) a[j] = 0ull;
    for (int j = 0; j < C_/4/256; ++j) {          // 8 float4 per thread
        int q = tid + j*256;
        float4 v = base[q];
        unsigned int i0 = (unsigned int)(c*C_ + q*4);
        unsigned long long k0 = pack_key(v.x, i0);
        if (k0 > a[9]) insert10(a, k0);
        unsigned long long k1 = pack_key(v.y, i0+1);
        if (k1 > a[9]) insert10(a, k1);
        unsigned long long k2 = pack_key(v.z, i0+2);
        if (k2 > a[9]) insert10(a, k2);
        unsigned long long k3 = pack_key(v.w, i0+3);
        if (k3 > a[9]) insert10(a, k3);
    }
    __shared__ unsigned long long sm[256*10];
    #pragma unroll
    for (int j = 0; j < 10; ++j) sm[tid*10+j] = a[j];
    __syncthreads();
    for (int st = 128; st >= 1; st >>= 1) {
        if (tid < st) {
            unsigned long long x[10], y[10];
            #pragma unroll
            for (int j = 0; j < 10; ++j) { x[j] = sm[tid*10+j]; y[j] = sm[(tid+st)*10+j]; }
            merge10(x, y);
            #pragma unroll
            for (int j = 0; j < 10; ++j) sm[tid*10+j] = x[j];
        }
        __syncthreads();
    }
    if (tid < 10) cand[(size_t)blockIdx.x*10 + tid] = sm[tid];
}

// ---------------- top-k phase 2: merge 34 lists, compute tv/pid ----------------
// grid = B*S, block 64
__global__ __launch_bounds__(64) void k_top2(const float* __restrict__ preds,
                                             const float* __restrict__ gsk,
                                             const unsigned long long* __restrict__ cand,
                                             float* __restrict__ ws_tv,
                                             int* __restrict__ ws_pid) {
    int bs = blockIdx.x; int s = bs % S_; int b = bs / S_;
    int tid = threadIdx.x;
    __shared__ unsigned long long sm[64*10];
    if (tid < G_) {
        #pragma unroll
        for (int j = 0; j < 10; ++j) sm[tid*10+j] = cand[((size_t)bs*G_ + tid)*10 + j];
    } else {
        #pragma unroll
        for (int j = 0; j < 10; ++j) sm[tid*10+j] = 0ull;
    }
    __syncthreads();
    for (int st = 32; st >= 1; st >>= 1) {
        if (tid < st) {
            unsigned long long x[10], y[10];
            #pragma unroll
            for (int j = 0; j < 10; ++j) { x[j] = sm[tid*10+j]; y[j] = sm[(tid+st)*10+j]; }
            merge10(x, y);
            #pragma unroll
            for (int j = 0; j < 10; ++j) sm[tid*10+j] = x[j];
        }
        __syncthreads();
    }
    if (tid < K_) {
        unsigned long long key = sm[tid];
        unsigned int topi = (unsigned int)(~key);    // recover index
        int part = topi >> 14;                       // / HW_
        int rem  = topi & (HW_-1);
        int xi   = rem >> 7;
        int yi   = rem & (W_-1);
        const float* tagbase = preds + ((size_t)bs*CH_ + P_)*HW_;
        float tv = tagbase[topi];
        float best = INFINITY; int pid = 0;
        for (int m = 0; m < M_; m++) {
            const float* sk = gsk + ((size_t)(b*M_ + m)*P_ + part)*3;
            float sk1 = sk[1], sk2 = sk[2];
            float vp = (sk2 == 1.0f) ? MAXDIST : 0.0f;
            float d0 = vp + sk1 - (float)xi;
            float d1 = vp + sk2 - (float)yi;
            float dist = sqrtf(d0*d0 + d1*d1 + 1e-12f);
            if (dist < best) { best = dist; pid = m; }
        }
        int o = bs*K_ + tid;
        ws_tv[o]  = tv;
        ws_pid[o] = pid;
    }
}

// ---------------- det_loss ----------------
// grid = 544, block 256, 4 float4 per thread
__global__ __launch_bounds__(256) void k_det(const float* __restrict__ preds,
                                             const float* __restrict__ gmask,
                                             const float* __restrict__ gh,
                                             float* __restrict__ out) {
    const int N4 = B_*S_*P_*HW_/4;                  // 557056
    float acc = 0.0f;
    for (int q = blockIdx.x*256 + threadIdx.x; q < N4; q += 544*256) {
        int hw4 = q & 4095;
        int t1  = q >> 12;
        int p   = t1 % P_;
        int t2  = t1 / P_;
        int s   = t2 & (S_-1);
        int b   = t2 >> 1;
        float4 hm4 = ((const float4*)preds)[((b*S_+s)*CH_ + p)*4096 + hw4];
        float4 gm4 = ((const float4*)gmask)[b*4096 + hw4];
        float4 gh4 = ((const float4*)gh)[(b*P_ + p)*4096 + hw4];
        const float* hmv = &hm4.x; const float* gmv = &gm4.x; const float* ghv4 = &gh4.x;
        #pragma unroll
        for (int cc = 0; cc < 4; ++cc) {
            float hm = hmv[cc];
            float e = exp2f(-fabsf(hm)*LOG2E);
            float r = __builtin_amdgcn_rcpf(1.0f + e);
            float prob = (hm >= 0.0f) ? r : e*r;
            float x = prob * gmv[cc];
            float ghv = ghv4[cc];
            float t   = (ghv > E_INV_F) ? 1.0f : 0.0f;
            float wgt = 10.0f*t + ((ghv < E_INV_F) ? 0.5f : 0.0f);
            float lx  = fmaxf(__logf(x),        -100.0f);
            float l1x = fmaxf(__logf(1.0f - x), -100.0f);
            acc += wgt * (-(t*lx + (1.0f - t)*l1x));
        }
    }
    #pragma unroll
    for (int off = 32; off > 0; off >>= 1) acc += __shfl_down(acc, off);
    __shared__ float sred[4];
    int wave = threadIdx.x >> 6, lane = threadIdx.x & 63;
    if (lane == 0) sred[wave] = acc;
    __syncthreads();
    if (threadIdx.x == 0) {
        float sum = sred[0] + sred[1] + sred[2] + sred[3];
        atomicAdd(out, sum * (1.0f/(float)(B_*S_*P_*HW_)));
    }
}

// ---------------- push/pull tag loss ----------------
__global__ __launch_bounds__(256) void k_tag(const float* __restrict__ preds,
                                             const int* __restrict__ kp,
                                             float* __restrict__ out) {
    int bs = blockIdx.x; int b = bs / S_;
    __shared__ float g[M_*P_];
    __shared__ float vis[M_*P_];
    __shared__ float mean_tag[M_];
    __shared__ float validm[M_];
    __shared__ float pull_pp[M_];
    int tid = threadIdx.x;
    const float* tagbase = preds + ((size_t)bs*CH_ + P_)*HW_;
    if (tid < M_*P_) {
        int m = tid / P_; int p = tid % P_;
        int off = ((b*M_ + m)*P_ + p)*2;
        int idx = kp[off];
        int v   = kp[off+1];
        g[tid]   = tagbase[idx];
        vis[tid] = (v > 0) ? 1.0f : 0.0f;
    }
    __syncthreads();
    if (tid < M_) {
        float cnt = 0.0f, sum = 0.0f;
        for (int p = 0; p < P_; p++) { cnt += vis[tid*P_+p]; sum += g[tid*P_+p]*vis[tid*P_+p]; }
        float safe = fmaxf(cnt, 1.0f);
        float mt = sum / safe;
        mean_tag[tid] = mt;
        validm[tid] = (cnt > 0.0f) ? 1.0f : 0.0f;
        float pp = 0.0f;
        for (int p = 0; p < P_; p++) { float d = g[tid*P_+p] - mt; pp += d*d*vis[tid*P_+p]; }
        pull_pp[tid] = pp / safe;
    }
    __syncthreads();
    if (tid == 0) {
        float num = 0.0f;
        for (int m = 0; m < M_; m++) num += validm[m];
        float pull = 0.0f;
        for (int m = 0; m < M_; m++) pull += pull_pp[m]*validm[m];
        pull = pull / (num + 1e-6f);
        float pmsum = 0.0f;
        for (int i = 0; i < M_; i++)
            for (int j = 0; j < M_; j++) {
                float d = mean_tag[i] - mean_tag[j]; d = d*d;
                pmsum += expf(-d)*validm[i]*validm[j];
            }
        float push = (pmsum - num) / ((num - 1.0f)*num + 1e-6f) * 0.5f;
        atomicAdd(out, (push + pull) * (1.0f/(float)(B_*S_)));
    }
}

// ---------------- skel loss: one block per (b,s,p); no online max ----------------
__global__ __launch_bounds__(256) void k_skel(const float* __restrict__ preds,
                                              const float* __restrict__ gsk,
                                              const float* __restrict__ ws_tv,
                                              const int* __restrict__ ws_pid,
                                              float* __restrict__ out) {
    int bid = blockIdx.x;                 // over B*S*P
    int p  = bid % P_;
    int bs = bid / P_;
    int b  = bs / S_;
    const float4* hm4 = (const float4*)(preds + ((size_t)bs*CH_ + p)*HW_);
    const float4* tg4 = (const float4*)(preds + ((size_t)bs*CH_ + P_ + p)*HW_);
    float tv[K_];
    #pragma unroll
    for (int k = 0; k < K_; k++) tv[k] = ws_tv[bs*K_ + k];
    float l[K_], sx[K_], sy[K_];
    #pragma unroll
    for (int k = 0; k < K_; k++) { l[k] = 0.0f; sx[k] = 0.0f; sy[k] = 0.0f; }
    int tid = threadIdx.x;
    const float C2 = INV2SIG * LOG2E;     // exp(z) == exp2(z*log2e)
    for (int j = 0; j < HW_/4/256; ++j) { // 16 float4 per thread
        int q = tid + j*256;
        float4 hv = hm4[q];
        float4 tg = tg4[q];
        float h  = (float)(q >> 5);           // row of this float4 (constant within)
        float w0 = (float)((q*4) & (W_-1));   // col of lane .x
        const float* hvv = &hv.x; const float* tgv = &tg.x;
        #pragma unroll
        for (int cc = 0; cc < 4; ++cc) {
            float a2 = (SF_*LOG2E) * hvv[cc];
            float tgc = tgv[cc];
            float w = w0 + (float)cc;
            #pragma unroll
            for (int k = 0; k < K_; k++) {
                float d = tgc - tv[k];
                float e = exp2f(fmaf(-C2, d*d, a2));
                l[k] += e;
                sx[k] = fmaf(e, h, sx[k]);
                sy[k] = fmaf(e, w, sy[k]);
            }
        }
    }
    #pragma unroll
    for (int k = 0; k < K_; k++) {
        for (int off = 32; off > 0; off >>= 1) {
            l[k]  += __shfl_down(l[k],  off);
            sx[k] += __shfl_down(sx[k], off);
            sy[k] += __shfl_down(sy[k], off);
        }
    }
    __shared__ float red[4][K_][3];
    int wave = tid >> 6, lane = tid & 63;
    if (lane == 0) {
        for (int k = 0; k < K_; k++) {
            red[wave][k][0] = l[k]; red[wave][k][1] = sx[k]; red[wave][k][2] = sy[k];
        }
    }
    __syncthreads();
    if (tid < K_) {
        int k = tid;
        float L  = red[0][k][0] + red[1][k][0] + red[2][k][0] + red[3][k][0];
        float SX = red[0][k][1] + red[1][k][1] + red[2][k][1] + red[3][k][1];
        float SY = red[0][k][2] + red[1][k][2] + red[2][k][2] + red[3][k][2];
        float px = SX / L, py = SY / L;
        int pid = ws_pid[bs*K_ + k];
        const float* g = gsk + ((size_t)(b*M_ + pid)*P_ + p)*3;
        float d0 = g[0] - px, d1 = g[1] - py;
        float gate = (g[2] > 0.0f) ? 1.0f : 0.0f;
        float err = sqrtf(d0*d0 + d1*d1 + 1e-12f) * gate;
        float hub = (err < 0.1f) ? err*err : 0.1f*(err - 0.05f);
        atomicAdd(out, hub * (10.0f/(float)(B_*S_*K_*P_)));
    }
}

extern "C" void kernel_launch(void* const* d_in, const int* in_sizes, int n_in,
                              void* d_out, int out_size, void* d_ws, size_t ws_size,
                              hipStream_t stream) {
    (void)in_sizes; (void)n_in; (void)out_size; (void)ws_size;
    const float* preds = (const float*)d_in[0];
    const float* gmask = (const float*)d_in[1];
    const float* gh    = (const float*)d_in[2];
    const float* gsk   = (const float*)d_in[3];
    const int*   gkp   = (const int*)d_in[4];
    float* out = (float*)d_out;
    unsigned long long* cand = (unsigned long long*)d_ws;            // B*S*G_*10 u64
    float* ws_tv  = (float*)(cand + (size_t)B_*S_*G_*10);            // B*S*K floats
    int*   ws_pid = (int*)(ws_tv + (size_t)B_*S_*K_);                // B*S*K ints

    hipLaunchKernelGGL(k_top1, dim3(B_*S_*G_), dim3(256), 0, stream, preds, cand, out);
    hipLaunchKernelGGL(k_det,  dim3(544),      dim3(256), 0, stream, preds, gmask, gh, out);
    hipLaunchKernelGGL(k_tag,  dim3(B_*S_),    dim3(256), 0, stream, preds, gkp, out);
    hipLaunchKernelGGL(k_top2, dim3(B_*S_),    dim3(64),  0, stream, preds, gsk, cand, ws_tv, ws_pid);
    hipLaunchKernelGGL(k_skel, dim3(B_*S_*P_), dim3(256), 0, stream, preds, gsk, ws_tv, ws_pid, out);
}

// Round 3
// 160.346 us; speedup vs baseline: 4.7565x; 1.0135x over previous
//
#include <hip/hip_runtime.h>
#include <math.h>

#define B_ 4
#define S_ 2
#define P_ 17
#define H_ 128
#define W_ 128
#define M_ 8
#define K_ 10
#define HW_ (H_*W_)
#define PHW_ (P_*HW_)
#define CH_ 34                 // (1+TAG)*P channels in preds
#define G_ 34                  // chunks per (b,s) for top-k phase 1
#define C_ (PHW_/G_)           // 8192 elements per chunk
#define E_INV_F 0.36787944117144233f
#define LOG2E 1.4426950408889634f
#define SF_ 3.0f
#define INV2SIG 12.5f          // 1/(2*0.2^2)
#define MAXDIST 256.0f         // H+W

#define TOP1_BLOCKS (B_*S_*G_)   // 272
#define DET_BLOCKS  544
#define TAG_BLOCKS  (B_*S_)      // 8
#define MAIN_BLOCKS (TOP1_BLOCKS + DET_BLOCKS + TAG_BLOCKS)

// ---- packed sort key: monotone float map (hi) | ~index (lo) ----
// larger key == larger value, ties -> smaller index (matches jax top_k)
__device__ __forceinline__ unsigned int map32(float f) {
    unsigned int u = __float_as_uint(f);
    unsigned int flip = (unsigned int)((int)u >> 31) | 0x80000000u;
    return u ^ flip;
}

// branch-free insert into sorted-descending a[0..9]; caller guarantees key > a[9]
__device__ __forceinline__ void insert10(unsigned long long* a, unsigned long long key) {
    #pragma unroll
    for (int j = 9; j >= 1; --j) {
        unsigned long long am1 = a[j-1];
        a[j] = (key > am1) ? am1 : ((key > a[j]) ? key : a[j]);
    }
    a[0] = (key > a[0]) ? key : a[0];
}

// merge sorted list b into sorted list a (both desc, 10 entries)
__device__ __forceinline__ void merge10(unsigned long long* a, const unsigned long long* b) {
    #pragma unroll
    for (int t = 0; t < 10; ++t) {
        unsigned long long key = b[t];
        if (key > a[9]) insert10(a, key);
    }
}

// ================= fused main kernel: top1 scan | det loss | tag loss ============
__global__ __launch_bounds__(256) void k_main(const float* __restrict__ preds,
                                              const float* __restrict__ gmask,
                                              const float* __restrict__ gh,
                                              const int* __restrict__ kp,
                                              unsigned long long* __restrict__ cand,
                                              float* __restrict__ out) {
    int tid = threadIdx.x;
    if (blockIdx.x < TOP1_BLOCKS) {
        // -------- top-k phase 1: wave-cooperative ballot scan --------
        int bs = blockIdx.x / G_;
        int c  = blockIdx.x % G_;
        int wave = tid >> 6, lane = tid & 63;
        const float4* base = (const float4*)(preds + (size_t)bs*CH_*HW_ + (size_t)c*C_);
        unsigned long long a[10];
        #pragma unroll
        for (int j = 0; j < 10; ++j) a[j] = 0ull;
        for (int j = 0; j < 8; ++j) {                  // wave covers 2048 elements
            int idx4 = wave*512 + j*64 + lane;
            float4 v = base[idx4];
            unsigned int i0 = (unsigned int)(c*C_ + idx4*4);
            const float* vv = &v.x;
            #pragma unroll
            for (int cc = 0; cc < 4; ++cc) {
                unsigned int key32 = map32(vv[cc]);
                unsigned int thr = (unsigned int)(a[9] >> 32);
                unsigned long long mask = __ballot(key32 >= thr);
                if (mask) {
                    unsigned long long kk =
                        ((unsigned long long)key32 << 32) | (unsigned int)(~(i0 + cc));
                    do {
                        int l = (int)__ffsll(mask) - 1;
                        unsigned long long cnd = __shfl(kk, l);
                        if (cnd > a[9]) insert10(a, cnd);
                        mask &= mask - 1;
                    } while (mask);
                }
            }
        }
        __shared__ unsigned long long smw[4][10];
        if (lane == 0) {
            #pragma unroll
            for (int j = 0; j < 10; ++j) smw[wave][j] = a[j];
        }
        __syncthreads();
        if (tid < 2) {
            unsigned long long x[10], y[10];
            #pragma unroll
            for (int j = 0; j < 10; ++j) { x[j] = smw[tid][j]; y[j] = smw[tid+2][j]; }
            merge10(x, y);
            #pragma unroll
            for (int j = 0; j < 10; ++j) smw[tid][j] = x[j];
        }
        __syncthreads();
        if (tid == 0) {
            unsigned long long x[10], y[10];
            #pragma unroll
            for (int j = 0; j < 10; ++j) { x[j] = smw[0][j]; y[j] = smw[1][j]; }
            merge10(x, y);
            #pragma unroll
            for (int j = 0; j < 10; ++j) cand[(size_t)blockIdx.x*10 + j] = x[j];
        }
    } else if (blockIdx.x < TOP1_BLOCKS + DET_BLOCKS) {
        // -------- det loss --------
        int t = (blockIdx.x - TOP1_BLOCKS)*256 + tid;
        float acc = 0.0f;
        #pragma unroll
        for (int j = 0; j < 4; ++j) {                  // 4*139264 == N4 exactly
            int q = t + j*(DET_BLOCKS*256);
            int hw4 = q & 4095;
            int t1  = q >> 12;
            int p   = t1 % P_;
            int t2  = t1 / P_;
            float4 hm4 = ((const float4*)preds)[(t2*CH_ + p)*4096 + hw4];
            float4 gm4 = ((const float4*)gmask)[(t2>>1)*4096 + hw4];
            float4 gh4 = ((const float4*)gh)[((t2>>1)*P_ + p)*4096 + hw4];
            const float* hmv = &hm4.x; const float* gmv = &gm4.x; const float* ghv4 = &gh4.x;
            #pragma unroll
            for (int cc = 0; cc < 4; ++cc) {
                float hm = hmv[cc];
                float e = exp2f(-fabsf(hm)*LOG2E);
                float r = __builtin_amdgcn_rcpf(1.0f + e);
                float prob = (hm >= 0.0f) ? r : e*r;
                float x = prob * gmv[cc];
                float ghv = ghv4[cc];
                float tt  = (ghv > E_INV_F) ? 1.0f : 0.0f;
                float wgt = 10.0f*tt + ((ghv < E_INV_F) ? 0.5f : 0.0f);
                float lx  = fmaxf(__logf(x),        -100.0f);
                float l1x = fmaxf(__logf(1.0f - x), -100.0f);
                acc += wgt * (-(tt*lx + (1.0f - tt)*l1x));
            }
        }
        #pragma unroll
        for (int off = 32; off > 0; off >>= 1) acc += __shfl_down(acc, off);
        __shared__ float sred[4];
        int wave = tid >> 6, lane = tid & 63;
        if (lane == 0) sred[wave] = acc;
        __syncthreads();
        if (tid == 0) {
            float sum = sred[0] + sred[1] + sred[2] + sred[3];
            atomicAdd(out, sum * (1.0f/(float)(B_*S_*P_*HW_)));
        }
    } else {
        // -------- push/pull tag loss --------
        int bs = blockIdx.x - (TOP1_BLOCKS + DET_BLOCKS);
        int b = bs / S_;
        __shared__ float g[M_*P_];
        __shared__ float vis[M_*P_];
        __shared__ float mean_tag[M_];
        __shared__ float validm[M_];
        __shared__ float pull_pp[M_];
        const float* tagbase = preds + ((size_t)bs*CH_ + P_)*HW_;
        if (tid < M_*P_) {
            int m = tid / P_; int p = tid % P_;
            int off = ((b*M_ + m)*P_ + p)*2;
            int idx = kp[off];
            int v   = kp[off+1];
            g[tid]   = tagbase[idx];
            vis[tid] = (v > 0) ? 1.0f : 0.0f;
        }
        __syncthreads();
        if (tid < M_) {
            float cnt = 0.0f, sum = 0.0f;
            for (int p = 0; p < P_; p++) { cnt += vis[tid*P_+p]; sum += g[tid*P_+p]*vis[tid*P_+p]; }
            float safe = fmaxf(cnt, 1.0f);
            float mt = sum / safe;
            mean_tag[tid] = mt;
            validm[tid] = (cnt > 0.0f) ? 1.0f : 0.0f;
            float pp = 0.0f;
            for (int p = 0; p < P_; p++) { float d = g[tid*P_+p] - mt; pp += d*d*vis[tid*P_+p]; }
            pull_pp[tid] = pp / safe;
        }
        __syncthreads();
        if (tid == 0) {
            float num = 0.0f;
            for (int m = 0; m < M_; m++) num += validm[m];
            float pull = 0.0f;
            for (int m = 0; m < M_; m++) pull += pull_pp[m]*validm[m];
            pull = pull / (num + 1e-6f);
            float pmsum = 0.0f;
            for (int i = 0; i < M_; i++)
                for (int j = 0; j < M_; j++) {
                    float d = mean_tag[i] - mean_tag[j]; d = d*d;
                    pmsum += expf(-d)*validm[i]*validm[j];
                }
            float push = (pmsum - num) / ((num - 1.0f)*num + 1e-6f) * 0.5f;
            atomicAdd(out, (push + pull) * (1.0f/(float)(B_*S_)));
        }
    }
}

// ---------------- top-k phase 2: merge 34 lists, compute tv/pid ----------------
__global__ __launch_bounds__(64) void k_top2(const float* __restrict__ preds,
                                             const float* __restrict__ gsk,
                                             const unsigned long long* __restrict__ cand,
                                             float* __restrict__ ws_tv,
                                             int* __restrict__ ws_pid) {
    int bs = blockIdx.x; int b = bs / S_;
    int tid = threadIdx.x;
    __shared__ unsigned long long sm[64*10];
    if (tid < G_) {
        #pragma unroll
        for (int j = 0; j < 10; ++j) sm[tid*10+j] = cand[((size_t)bs*G_ + tid)*10 + j];
    } else {
        #pragma unroll
        for (int j = 0; j < 10; ++j) sm[tid*10+j] = 0ull;
    }
    __syncthreads();
    for (int st = 32; st >= 1; st >>= 1) {
        if (tid < st) {
            unsigned long long x[10], y[10];
            #pragma unroll
            for (int j = 0; j < 10; ++j) { x[j] = sm[tid*10+j]; y[j] = sm[(tid+st)*10+j]; }
            merge10(x, y);
            #pragma unroll
            for (int j = 0; j < 10; ++j) sm[tid*10+j] = x[j];
        }
        __syncthreads();
    }
    if (tid < K_) {
        unsigned long long key = sm[tid];
        unsigned int topi = (unsigned int)(~key);    // recover index
        int part = topi >> 14;                       // / HW_
        int rem  = topi & (HW_-1);
        int xi   = rem >> 7;
        int yi   = rem & (W_-1);
        const float* tagbase = preds + ((size_t)bs*CH_ + P_)*HW_;
        float tv = tagbase[topi];
        float best = INFINITY; int pid = 0;
        for (int m = 0; m < M_; m++) {
            const float* sk = gsk + ((size_t)(b*M_ + m)*P_ + part)*3;
            float sk1 = sk[1], sk2 = sk[2];
            float vp = (sk2 == 1.0f) ? MAXDIST : 0.0f;
            float d0 = vp + sk1 - (float)xi;
            float d1 = vp + sk2 - (float)yi;
            float dist = sqrtf(d0*d0 + d1*d1 + 1e-12f);
            if (dist < best) { best = dist; pid = m; }
        }
        int o = bs*K_ + tid;
        ws_tv[o]  = tv;
        ws_pid[o] = pid;
    }
}

// ---------------- skel loss: one block (1024 thr) per (b,s,p) ----------------
__global__ __launch_bounds__(1024) void k_skel(const float* __restrict__ preds,
                                               const float* __restrict__ gsk,
                                               const float* __restrict__ ws_tv,
                                               const int* __restrict__ ws_pid,
                                               float* __restrict__ out) {
    int bid = blockIdx.x;                 // over B*S*P
    int p  = bid % P_;
    int bs = bid / P_;
    int b  = bs / S_;
    const float4* hm4 = (const float4*)(preds + ((size_t)bs*CH_ + p)*HW_);
    const float4* tg4 = (const float4*)(preds + ((size_t)bs*CH_ + P_ + p)*HW_);
    float tv[K_];
    #pragma unroll
    for (int k = 0; k < K_; k++) tv[k] = ws_tv[bs*K_ + k];
    float l[K_], sx[K_], sy[K_];
    #pragma unroll
    for (int k = 0; k < K_; k++) { l[k] = 0.0f; sx[k] = 0.0f; sy[k] = 0.0f; }
    int tid = threadIdx.x;
    const float C2 = INV2SIG * LOG2E;     // exp(z) == exp2(z*log2e)
    #pragma unroll
    for (int j = 0; j < HW_/4/1024; ++j) {  // 4 float4 per thread
        int q = tid + j*1024;
        float4 hv = hm4[q];
        float4 tg = tg4[q];
        float h  = (float)(q >> 5);           // row of this float4
        float w0 = (float)((q*4) & (W_-1));   // col of component .x
        const float* hvv = &hv.x; const float* tgv = &tg.x;
        #pragma unroll
        for (int cc = 0; cc < 4; ++cc) {
            float a2 = (SF_*LOG2E) * hvv[cc];
            float tgc = tgv[cc];
            float w = w0 + (float)cc;
            #pragma unroll
            for (int k = 0; k < K_; k++) {
                float d = tgc - tv[k];
                float e = exp2f(fmaf(-C2, d*d, a2));
                l[k] += e;
                sx[k] = fmaf(e, h, sx[k]);
                sy[k] = fmaf(e, w, sy[k]);
            }
        }
    }
    #pragma unroll
    for (int k = 0; k < K_; k++) {
        for (int off = 32; off > 0; off >>= 1) {
            l[k]  += __shfl_down(l[k],  off);
            sx[k] += __shfl_down(sx[k], off);
            sy[k] += __shfl_down(sy[k], off);
        }
    }
    __shared__ float red[16][K_][3];
    int wave = tid >> 6, lane = tid & 63;
    if (lane == 0) {
        for (int k = 0; k < K_; k++) {
            red[wave][k][0] = l[k]; red[wave][k][1] = sx[k]; red[wave][k][2] = sy[k];
        }
    }
    __syncthreads();
    __shared__ float hubred[K_];
    if (tid < K_) {
        int k = tid;
        float L = 0.0f, SX = 0.0f, SY = 0.0f;
        #pragma unroll
        for (int w2 = 0; w2 < 16; w2++) {
            L += red[w2][k][0]; SX += red[w2][k][1]; SY += red[w2][k][2];
        }
        float px = SX / L, py = SY / L;
        int pid = ws_pid[bs*K_ + k];
        const float* g = gsk + ((size_t)(b*M_ + pid)*P_ + p)*3;
        float d0 = g[0] - px, d1 = g[1] - py;
        float gate = (g[2] > 0.0f) ? 1.0f : 0.0f;
        float err = sqrtf(d0*d0 + d1*d1 + 1e-12f) * gate;
        float hub = (err < 0.1f) ? err*err : 0.1f*(err - 0.05f);
        hubred[k] = hub;
    }
    __syncthreads();
    if (tid == 0) {
        float s = 0.0f;
        #pragma unroll
        for (int k = 0; k < K_; k++) s += hubred[k];
        atomicAdd(out, s * (10.0f/(float)(B_*S_*K_*P_)));
    }
}

extern "C" void kernel_launch(void* const* d_in, const int* in_sizes, int n_in,
                              void* d_out, int out_size, void* d_ws, size_t ws_size,
                              hipStream_t stream) {
    (void)in_sizes; (void)n_in; (void)out_size; (void)ws_size;
    const float* preds = (const float*)d_in[0];
    const float* gmask = (const float*)d_in[1];
    const float* gh    = (const float*)d_in[2];
    const float* gsk   = (const float*)d_in[3];
    const int*   gkp   = (const int*)d_in[4];
    float* out = (float*)d_out;
    unsigned long long* cand = (unsigned long long*)d_ws;            // B*S*G_*10 u64
    float* ws_tv  = (float*)(cand + (size_t)B_*S_*G_*10);            // B*S*K floats
    int*   ws_pid = (int*)(ws_tv + (size_t)B_*S_*K_);                // B*S*K ints

    hipMemsetAsync(out, 0, sizeof(float), stream);
    hipLaunchKernelGGL(k_main, dim3(MAIN_BLOCKS), dim3(256), 0, stream,
                       preds, gmask, gh, gkp, cand, out);
    hipLaunchKernelGGL(k_top2, dim3(B_*S_),    dim3(64),   0, stream, preds, gsk, cand, ws_tv, ws_pid);
    hipLaunchKernelGGL(k_skel, dim3(B_*S_*P_), dim3(1024), 0, stream, preds, gsk, ws_tv, ws_pid, out);
}

// Round 4
// 130.227 us; speedup vs baseline: 5.8565x; 1.2313x over previous
//
#include <hip/hip_runtime.h>
#include <math.h>

#define B_ 4
#define S_ 2
#define P_ 17
#define H_ 128
#define W_ 128
#define M_ 8
#define K_ 10
#define HW_ (H_*W_)
#define PHW_ (P_*HW_)
#define CH_ 34                 // (1+TAG)*P channels in preds
#define G_ 34                  // chunks per (b,s) for top-k phase 1
#define C_ (PHW_/G_)           // 8192 elements per chunk
#define E_INV_F 0.36787944117144233f
#define LOG2E 1.4426950408889634f
#define SF_ 3.0f
#define INV2SIG 12.5f          // 1/(2*0.2^2)
#define MAXDIST 256.0f         // H+W

#define TOP1_BLOCKS (B_*S_*G_)   // 272
#define DET_BLOCKS  544
#define TAG_BLOCKS  (B_*S_)      // 8
#define MAIN_BLOCKS (TOP1_BLOCKS + DET_BLOCKS + TAG_BLOCKS)

#define SKEL_CHUNKS 4
#define NBSP (B_*S_*P_)                      // 136
#define SKEL_BLOCKS (NBSP*SKEL_CHUNKS)       // 544

// ---- packed sort key: monotone float map (hi) | ~index (lo) ----
__device__ __forceinline__ unsigned int map32(float f) {
    unsigned int u = __float_as_uint(f);
    unsigned int flip = (unsigned int)((int)u >> 31) | 0x80000000u;
    return u ^ flip;
}

// branch-free insert into sorted-descending a[0..9]; caller guarantees key > a[9]
__device__ __forceinline__ void insert10(unsigned long long* a, unsigned long long key) {
    #pragma unroll
    for (int j = 9; j >= 1; --j) {
        unsigned long long am1 = a[j-1];
        a[j] = (key > am1) ? am1 : ((key > a[j]) ? key : a[j]);
    }
    a[0] = (key > a[0]) ? key : a[0];
}

__device__ __forceinline__ void merge10(unsigned long long* a, const unsigned long long* b) {
    #pragma unroll
    for (int t = 0; t < 10; ++t) {
        unsigned long long key = b[t];
        if (key > a[9]) insert10(a, key);
    }
}

// ================= fused main kernel: top1 scan | det partial | tag partial ======
__global__ __launch_bounds__(256, 4) void k_main(const float* __restrict__ preds,
                                                 const float* __restrict__ gmask,
                                                 const float* __restrict__ gh,
                                                 const int* __restrict__ kp,
                                                 unsigned long long* __restrict__ cand,
                                                 float* __restrict__ ws_det,
                                                 float* __restrict__ ws_tag) {
    int tid = threadIdx.x;
    if (blockIdx.x < TOP1_BLOCKS) {
        // -------- top-k phase 1: wave-cooperative ballot scan --------
        int bs = blockIdx.x / G_;
        int c  = blockIdx.x % G_;
        int wave = tid >> 6, lane = tid & 63;
        const float4* base = (const float4*)(preds + (size_t)bs*CH_*HW_ + (size_t)c*C_);
        unsigned long long a[10];
        #pragma unroll
        for (int j = 0; j < 10; ++j) a[j] = 0ull;
        for (int j = 0; j < 8; ++j) {                  // wave covers 2048 elements
            int idx4 = wave*512 + j*64 + lane;
            float4 v = base[idx4];
            unsigned int i0 = (unsigned int)(c*C_ + idx4*4);
            const float* vv = &v.x;
            #pragma unroll
            for (int cc = 0; cc < 4; ++cc) {
                unsigned int key32 = map32(vv[cc]);
                unsigned int thr = (unsigned int)(a[9] >> 32);
                unsigned long long mask = __ballot(key32 >= thr);
                if (mask) {
                    unsigned long long kk =
                        ((unsigned long long)key32 << 32) | (unsigned int)(~(i0 + cc));
                    do {
                        int l = (int)__ffsll(mask) - 1;
                        unsigned long long cnd = __shfl(kk, l);
                        if (cnd > a[9]) insert10(a, cnd);
                        mask &= mask - 1;
                    } while (mask);
                }
            }
        }
        __shared__ unsigned long long smw[4][10];
        if (lane == 0) {
            #pragma unroll
            for (int j = 0; j < 10; ++j) smw[wave][j] = a[j];
        }
        __syncthreads();
        if (tid < 2) {
            unsigned long long x[10], y[10];
            #pragma unroll
            for (int j = 0; j < 10; ++j) { x[j] = smw[tid][j]; y[j] = smw[tid+2][j]; }
            merge10(x, y);
            #pragma unroll
            for (int j = 0; j < 10; ++j) smw[tid][j] = x[j];
        }
        __syncthreads();
        if (tid == 0) {
            unsigned long long x[10], y[10];
            #pragma unroll
            for (int j = 0; j < 10; ++j) { x[j] = smw[0][j]; y[j] = smw[1][j]; }
            merge10(x, y);
            #pragma unroll
            for (int j = 0; j < 10; ++j) cand[(size_t)blockIdx.x*10 + j] = x[j];
        }
    } else if (blockIdx.x < TOP1_BLOCKS + DET_BLOCKS) {
        // -------- det loss partial (no atomic; per-block partial to ws) --------
        int dblk = blockIdx.x - TOP1_BLOCKS;
        int t = dblk*256 + tid;
        float acc = 0.0f;
        #pragma unroll
        for (int j = 0; j < 4; ++j) {                  // 4*139264 == N4 exactly
            int q = t + j*(DET_BLOCKS*256);
            int hw4 = q & 4095;
            int t1  = q >> 12;
            int p   = t1 % P_;
            int t2  = t1 / P_;
            float4 hm4 = ((const float4*)preds)[(t2*CH_ + p)*4096 + hw4];
            float4 gm4 = ((const float4*)gmask)[(t2>>1)*4096 + hw4];
            float4 gh4 = ((const float4*)gh)[((t2>>1)*P_ + p)*4096 + hw4];
            const float* hmv = &hm4.x; const float* gmv = &gm4.x; const float* ghv4 = &gh4.x;
            #pragma unroll
            for (int cc = 0; cc < 4; ++cc) {
                float hm = hmv[cc];
                float e = exp2f(-fabsf(hm)*LOG2E);
                float r = __builtin_amdgcn_rcpf(1.0f + e);
                float prob = (hm >= 0.0f) ? r : e*r;
                float x = prob * gmv[cc];
                float ghv = ghv4[cc];
                float tt  = (ghv > E_INV_F) ? 1.0f : 0.0f;
                float wgt = 10.0f*tt + ((ghv < E_INV_F) ? 0.5f : 0.0f);
                float lx  = fmaxf(__logf(x),        -100.0f);
                float l1x = fmaxf(__logf(1.0f - x), -100.0f);
                acc += wgt * (-(tt*lx + (1.0f - tt)*l1x));
            }
        }
        #pragma unroll
        for (int off = 32; off > 0; off >>= 1) acc += __shfl_down(acc, off);
        __shared__ float sred[4];
        int wave = tid >> 6, lane = tid & 63;
        if (lane == 0) sred[wave] = acc;
        __syncthreads();
        if (tid == 0) ws_det[dblk] = sred[0] + sred[1] + sred[2] + sred[3];
    } else {
        // -------- push/pull tag loss partial --------
        int bs = blockIdx.x - (TOP1_BLOCKS + DET_BLOCKS);
        int b = bs / S_;
        __shared__ float g[M_*P_];
        __shared__ float vis[M_*P_];
        __shared__ float mean_tag[M_];
        __shared__ float validm[M_];
        __shared__ float pull_pp[M_];
        const float* tagbase = preds + ((size_t)bs*CH_ + P_)*HW_;
        if (tid < M_*P_) {
            int m = tid / P_; int p = tid % P_;
            int off = ((b*M_ + m)*P_ + p)*2;
            int idx = kp[off];
            int v   = kp[off+1];
            g[tid]   = tagbase[idx];
            vis[tid] = (v > 0) ? 1.0f : 0.0f;
        }
        __syncthreads();
        if (tid < M_) {
            float cnt = 0.0f, sum = 0.0f;
            for (int p = 0; p < P_; p++) { cnt += vis[tid*P_+p]; sum += g[tid*P_+p]*vis[tid*P_+p]; }
            float safe = fmaxf(cnt, 1.0f);
            float mt = sum / safe;
            mean_tag[tid] = mt;
            validm[tid] = (cnt > 0.0f) ? 1.0f : 0.0f;
            float pp = 0.0f;
            for (int p = 0; p < P_; p++) { float d = g[tid*P_+p] - mt; pp += d*d*vis[tid*P_+p]; }
            pull_pp[tid] = pp / safe;
        }
        __syncthreads();
        if (tid == 0) {
            float num = 0.0f;
            for (int m = 0; m < M_; m++) num += validm[m];
            float pull = 0.0f;
            for (int m = 0; m < M_; m++) pull += pull_pp[m]*validm[m];
            pull = pull / (num + 1e-6f);
            float pmsum = 0.0f;
            for (int i = 0; i < M_; i++)
                for (int j = 0; j < M_; j++) {
                    float d = mean_tag[i] - mean_tag[j]; d = d*d;
                    pmsum += expf(-d)*validm[i]*validm[j];
                }
            float push = (pmsum - num) / ((num - 1.0f)*num + 1e-6f) * 0.5f;
            ws_tag[bs] = push + pull;
        }
    }
}

// ---------------- top-k phase 2: merge 34 lists, compute tv/pid ----------------
__global__ __launch_bounds__(64) void k_top2(const float* __restrict__ preds,
                                             const float* __restrict__ gsk,
                                             const unsigned long long* __restrict__ cand,
                                             float* __restrict__ ws_tv,
                                             int* __restrict__ ws_pid) {
    int bs = blockIdx.x; int b = bs / S_;
    int tid = threadIdx.x;
    __shared__ unsigned long long sm[64*10];
    if (tid < G_) {
        #pragma unroll
        for (int j = 0; j < 10; ++j) sm[tid*10+j] = cand[((size_t)bs*G_ + tid)*10 + j];
    } else {
        #pragma unroll
        for (int j = 0; j < 10; ++j) sm[tid*10+j] = 0ull;
    }
    __syncthreads();
    for (int st = 32; st >= 1; st >>= 1) {
        if (tid < st) {
            unsigned long long x[10], y[10];
            #pragma unroll
            for (int j = 0; j < 10; ++j) { x[j] = sm[tid*10+j]; y[j] = sm[(tid+st)*10+j]; }
            merge10(x, y);
            #pragma unroll
            for (int j = 0; j < 10; ++j) sm[tid*10+j] = x[j];
        }
        __syncthreads();
    }
    if (tid < K_) {
        unsigned long long key = sm[tid];
        unsigned int topi = (unsigned int)(~key);    // recover index
        int part = topi >> 14;                       // / HW_
        int rem  = topi & (HW_-1);
        int xi   = rem >> 7;
        int yi   = rem & (W_-1);
        const float* tagbase = preds + ((size_t)bs*CH_ + P_)*HW_;
        float tv = tagbase[topi];
        float best = INFINITY; int pid = 0;
        for (int m = 0; m < M_; m++) {
            const float* sk = gsk + ((size_t)(b*M_ + m)*P_ + part)*3;
            float sk1 = sk[1], sk2 = sk[2];
            float vp = (sk2 == 1.0f) ? MAXDIST : 0.0f;
            float d0 = vp + sk1 - (float)xi;
            float d1 = vp + sk2 - (float)yi;
            float dist = sqrtf(d0*d0 + d1*d1 + 1e-12f);
            if (dist < best) { best = dist; pid = m; }
        }
        int o = bs*K_ + tid;
        ws_tv[o]  = tv;
        ws_pid[o] = pid;
    }
}

// ------- skel partial: (b,s,p) x 4 chunks, 256 threads, partials to ws -------
__global__ __launch_bounds__(256, 4) void k_skel(const float* __restrict__ preds,
                                                 const float* __restrict__ ws_tv,
                                                 float* __restrict__ ws_skl,
                                                 float* __restrict__ ws_ssx,
                                                 float* __restrict__ ws_ssy) {
    int bid   = blockIdx.x / SKEL_CHUNKS;   // over B*S*P
    int chunk = blockIdx.x % SKEL_CHUNKS;
    int p  = bid % P_;
    int bs = bid / P_;
    const float4* hm4 = (const float4*)(preds + ((size_t)bs*CH_ + p)*HW_);
    const float4* tg4 = (const float4*)(preds + ((size_t)bs*CH_ + P_ + p)*HW_);
    float tv[K_];
    #pragma unroll
    for (int k = 0; k < K_; k++) tv[k] = ws_tv[bs*K_ + k];
    float l[K_], sx[K_], sy[K_];
    #pragma unroll
    for (int k = 0; k < K_; k++) { l[k] = 0.0f; sx[k] = 0.0f; sy[k] = 0.0f; }
    int tid = threadIdx.x;
    const float C2 = INV2SIG * LOG2E;       // exp(z) == exp2(z*log2e)
    #pragma unroll
    for (int j = 0; j < 4; ++j) {           // 4 float4 per thread, 4096 px per chunk
        int q = chunk*1024 + j*256 + tid;   // global float4 index in [0,4096)
        float4 hv = hm4[q];
        float4 tg = tg4[q];
        float h  = (float)(q >> 5);         // row of this float4
        float w0 = (float)((q*4) & (W_-1)); // col of component .x
        const float* hvv = &hv.x; const float* tgv = &tg.x;
        #pragma unroll
        for (int cc = 0; cc < 4; ++cc) {
            float a2 = (SF_*LOG2E) * hvv[cc];
            float tgc = tgv[cc];
            float w = w0 + (float)cc;
            #pragma unroll
            for (int k = 0; k < K_; k++) {
                float d = tgc - tv[k];
                float e = exp2f(fmaf(-C2, d*d, a2));
                l[k] += e;
                sx[k] = fmaf(e, h, sx[k]);
                sy[k] = fmaf(e, w, sy[k]);
            }
        }
    }
    #pragma unroll
    for (int k = 0; k < K_; k++) {
        for (int off = 32; off > 0; off >>= 1) {
            l[k]  += __shfl_down(l[k],  off);
            sx[k] += __shfl_down(sx[k], off);
            sy[k] += __shfl_down(sy[k], off);
        }
    }
    __shared__ float red[4][K_][3];
    int wave = tid >> 6, lane = tid & 63;
    if (lane == 0) {
        #pragma unroll
        for (int k = 0; k < K_; k++) {
            red[wave][k][0] = l[k]; red[wave][k][1] = sx[k]; red[wave][k][2] = sy[k];
        }
    }
    __syncthreads();
    if (tid < K_) {
        int k = tid;
        float L  = red[0][k][0] + red[1][k][0] + red[2][k][0] + red[3][k][0];
        float SX = red[0][k][1] + red[1][k][1] + red[2][k][1] + red[3][k][1];
        float SY = red[0][k][2] + red[1][k][2] + red[2][k][2] + red[3][k][2];
        int o = blockIdx.x*K_ + k;
        ws_skl[o] = L; ws_ssx[o] = SX; ws_ssy[o] = SY;
    }
}

// ---------------- final reduce: det + tag + skel -> out[0] ----------------
__global__ __launch_bounds__(256) void k_fin(const float* __restrict__ gsk,
                                             const int* __restrict__ ws_pid,
                                             const float* __restrict__ ws_skl,
                                             const float* __restrict__ ws_ssx,
                                             const float* __restrict__ ws_ssy,
                                             const float* __restrict__ ws_det,
                                             const float* __restrict__ ws_tag,
                                             float* __restrict__ out) {
    int tid = threadIdx.x;
    float acc = 0.0f;
    // det: mean over all elements
    for (int i = tid; i < DET_BLOCKS; i += 256) acc += ws_det[i];
    acc *= (1.0f/(float)(B_*S_*P_*HW_));
    // tag: mean of per-(b,s) push+pull
    if (tid < B_*S_) acc += ws_tag[tid] * (1.0f/(float)(B_*S_));
    // skel: per (bid,k) combine 4 chunk partials
    for (int idx = tid; idx < NBSP*K_; idx += 256) {
        int bid = idx / K_;
        int k   = idx % K_;
        int p  = bid % P_;
        int bs = bid / P_;
        int b  = bs / S_;
        float L = 0.0f, SX = 0.0f, SY = 0.0f;
        #pragma unroll
        for (int c = 0; c < SKEL_CHUNKS; ++c) {
            int o = (bid*SKEL_CHUNKS + c)*K_ + k;
            L += ws_skl[o]; SX += ws_ssx[o]; SY += ws_ssy[o];
        }
        float px = SX / L, py = SY / L;
        int pid = ws_pid[bs*K_ + k];
        const float* g = gsk + ((size_t)(b*M_ + pid)*P_ + p)*3;
        float d0 = g[0] - px, d1 = g[1] - py;
        float gate = (g[2] > 0.0f) ? 1.0f : 0.0f;
        float err = sqrtf(d0*d0 + d1*d1 + 1e-12f) * gate;
        float hub = (err < 0.1f) ? err*err : 0.1f*(err - 0.05f);
        acc += hub * (10.0f/(float)(B_*S_*K_*P_));
    }
    #pragma unroll
    for (int off = 32; off > 0; off >>= 1) acc += __shfl_down(acc, off);
    __shared__ float sred[4];
    int wave = tid >> 6, lane = tid & 63;
    if (lane == 0) sred[wave] = acc;
    __syncthreads();
    if (tid == 0) out[0] = sred[0] + sred[1] + sred[2] + sred[3];
}

extern "C" void kernel_launch(void* const* d_in, const int* in_sizes, int n_in,
                              void* d_out, int out_size, void* d_ws, size_t ws_size,
                              hipStream_t stream) {
    (void)in_sizes; (void)n_in; (void)out_size; (void)ws_size;
    const float* preds = (const float*)d_in[0];
    const float* gmask = (const float*)d_in[1];
    const float* gh    = (const float*)d_in[2];
    const float* gsk   = (const float*)d_in[3];
    const int*   gkp   = (const int*)d_in[4];
    float* out = (float*)d_out;
    unsigned long long* cand = (unsigned long long*)d_ws;            // 2720 u64
    float* ws_tv  = (float*)(cand + (size_t)B_*S_*G_*10);            // 80 f
    int*   ws_pid = (int*)(ws_tv + (size_t)B_*S_*K_);                // 80 i
    float* ws_skl = (float*)(ws_pid + (size_t)B_*S_*K_);             // 5440 f
    float* ws_ssx = ws_skl + (size_t)SKEL_BLOCKS*K_;                 // 5440 f
    float* ws_ssy = ws_ssx + (size_t)SKEL_BLOCKS*K_;                 // 5440 f
    float* ws_det = ws_ssy + (size_t)SKEL_BLOCKS*K_;                 // 544 f
    float* ws_tag = ws_det + DET_BLOCKS;                             // 8 f

    hipLaunchKernelGGL(k_main, dim3(MAIN_BLOCKS), dim3(256), 0, stream,
                       preds, gmask, gh, gkp, cand, ws_det, ws_tag);
    hipLaunchKernelGGL(k_top2, dim3(B_*S_),       dim3(64),  0, stream,
                       preds, gsk, cand, ws_tv, ws_pid);
    hipLaunchKernelGGL(k_skel, dim3(SKEL_BLOCKS), dim3(256), 0, stream,
                       preds, ws_tv, ws_skl, ws_ssx, ws_ssy);
    hipLaunchKernelGGL(k_fin,  dim3(1),           dim3(256), 0, stream,
                       gsk, ws_pid, ws_skl, ws_ssx, ws_ssy, ws_det, ws_tag, out);
}